// Round 2
// baseline (283.099 us; speedup 1.0000x reference)
//
#include <hip/hip_runtime.h>

#define E_EDGES 1000000
#define NNODES  100000
#define HID     128
#define NTILES  (E_EDGES / 16)   // 62500 tiles of 16 edges, exact
#define NBLK    1024

typedef float f32x4 __attribute__((ext_vector_type(4)));
typedef short s16x8 __attribute__((ext_vector_type(8)));

// float -> bf16, round-to-nearest-even (inputs are finite)
__device__ __forceinline__ unsigned short f2bf(float f) {
  unsigned int u = __float_as_uint(f);
  u += 0x7FFFu + ((u >> 16) & 1u);
  return (unsigned short)(u >> 16);
}

__device__ __forceinline__ int4 pack8(float4 a, float4 b) {
  int4 v;
  v.x = (int)((unsigned)f2bf(a.x) | ((unsigned)f2bf(a.y) << 16));
  v.y = (int)((unsigned)f2bf(a.z) | ((unsigned)f2bf(a.w) << 16));
  v.z = (int)((unsigned)f2bf(b.x) | ((unsigned)f2bf(b.y) << 16));
  v.w = (int)((unsigned)f2bf(b.z) | ((unsigned)f2bf(b.w) << 16));
  return v;
}

// x fp32 [NNODES*HID] -> bf16 in ws. 12.8M elems / 8 per thread = 1.6M threads exact.
__global__ void cast_x_kernel(const float* __restrict__ x,
                              unsigned short* __restrict__ xb) {
  int i = blockIdx.x * blockDim.x + threadIdx.x;
  const float4* p = (const float4*)x;
  float4 a = p[2 * i];
  float4 b = p[2 * i + 1];
  int4 v = pack8(a, b);
  ((int4*)xb)[i] = v;
}

// Block = 256 threads = 4 waves. Each block grid-strides over 16-edge tiles.
// LDS layouts are MFMA-A "chunk" layout: 16B chunk c (k=8c..8c+7), row m at
// byte offset (c*16+m)*16  =>  ds_read_b128 at ((kstep*4+quad)*16 + m)*16
// yields A[m=lane&15][k=kstep*32+quad*8+j] exactly (verified m120 A-layout).
template <bool PRE>
__launch_bounds__(256, 2)
__global__ void edge_mlp_kernel(const unsigned short* __restrict__ xb,
                                const float* __restrict__ xf,
                                const int* __restrict__ ei,
                                const float* __restrict__ attr,
                                const float* __restrict__ W1,
                                const float* __restrict__ b1,
                                const float* __restrict__ W2,
                                const float* __restrict__ b2,
                                const float* __restrict__ W3,
                                const float* __restrict__ b3,
                                float* __restrict__ out) {
  __shared__ __align__(16) unsigned short ef[16 * 256];   // 8 KB: [chunk c][row m][8 bf16]
  __shared__ __align__(16) unsigned short h1b[16 * 128];  // 4 KB: same layout, K=128
  __shared__ float red[2][16];

  const int tid  = threadIdx.x;
  const int wave = tid >> 6;
  const int lane = tid & 63;
  const int quad = lane >> 4;
  const int l15  = lane & 15;

  // ---- per-block weight fragments (registers), loaded once ----
  // Wave w owns output columns 32w..32w+31 of layer 1 (2 N-tiles of 16).
  // B-frag for 16x16x32: B[k][n], n = lane&15, k = quad*8 + j (within K=32).
  s16x8 B1[2][8];
  float b1v[2], w1l[2];
#pragma unroll
  for (int t = 0; t < 2; ++t) {
    const int nc = (wave * 2 + t) * 16 + l15;
#pragma unroll
    for (int s = 0; s < 8; ++s) {
#pragma unroll
      for (int j = 0; j < 8; ++j)
        B1[t][s][j] = (short)f2bf(W1[(s * 32 + quad * 8 + j) * HID + nc]);
    }
    b1v[t] = b1[nc];
    w1l[t] = W1[256 * HID + nc];   // edge_attr column of W1 (k = 256)
  }
  s16x8 B2[4];
  float b2v = 0.f, w3v = 0.f;
  if (wave < 2) {                  // waves 0,1 own layer-2 cols 0..15 / 16..31
    const int n2 = wave * 16 + l15;
#pragma unroll
    for (int s = 0; s < 4; ++s)
#pragma unroll
      for (int j = 0; j < 8; ++j)
        B2[s][j] = (short)f2bf(W2[(s * 32 + quad * 8 + j) * 32 + n2]);
    b2v = b2[n2];
    w3v = W3[n2];
  }
  const float b3v = b3[0];

  // staging: lane owns chunks c0,c1; chunk<16 => src half, else dst half
  const int c0 = 8 * wave + quad;
  const int c1 = c0 + 4;

  int tile = blockIdx.x;
  int4 pv[2];
  float4 pa[2], pb[2];
  float attrv[4] = {0.f, 0.f, 0.f, 0.f};
  int nd2[2] = {0, 0};

  // ---- pipeline prologue ----
  if (tile < NTILES) {
    int n0 = ei[(c0 >> 4) * E_EDGES + tile * 16 + l15];
    int n1 = ei[(c1 >> 4) * E_EDGES + tile * 16 + l15];
    if constexpr (PRE) {
      pv[0] = *(const int4*)(xb + n0 * HID + (c0 & 15) * 8);
      pv[1] = *(const int4*)(xb + n1 * HID + (c1 & 15) * 8);
    } else {
      const float4* s0 = (const float4*)(xf + n0 * HID + (c0 & 15) * 8);
      const float4* s1 = (const float4*)(xf + n1 * HID + (c1 & 15) * 8);
      pa[0] = s0[0]; pb[0] = s0[1];
      pa[1] = s1[0]; pb[1] = s1[1];
    }
#pragma unroll
    for (int r = 0; r < 4; ++r) attrv[r] = attr[tile * 16 + quad * 4 + r];
    int t1 = tile + NBLK;
    if (t1 < NTILES) {
      nd2[0] = ei[(c0 >> 4) * E_EDGES + t1 * 16 + l15];
      nd2[1] = ei[(c1 >> 4) * E_EDGES + t1 * 16 + l15];
    }
  }

  for (; tile < NTILES; tile += NBLK) {
    // 1) deposit current tile's gathered rows into LDS (single buffer is safe:
    //    all reads of ef from the previous iteration are fenced by 2 barriers)
    {
      int4 v0, v1;
      if constexpr (PRE) { v0 = pv[0]; v1 = pv[1]; }
      else               { v0 = pack8(pa[0], pb[0]); v1 = pack8(pa[1], pb[1]); }
      *(int4*)&ef[(c0 * 16 + l15) * 8] = v0;
      *(int4*)&ef[(c1 * 16 + l15) * 8] = v1;
    }
    __syncthreads();

    // 2) prefetch next tile: gather with node-ids loaded last iteration,
    //    then issue node-id loads two tiles ahead. Consumed next iteration,
    //    so global latency hides under this iteration's compute.
    const int t1 = tile + NBLK;
    float attrn[4] = {0.f, 0.f, 0.f, 0.f};
    if (t1 < NTILES) {
      if constexpr (PRE) {
        pv[0] = *(const int4*)(xb + nd2[0] * HID + (c0 & 15) * 8);
        pv[1] = *(const int4*)(xb + nd2[1] * HID + (c1 & 15) * 8);
      } else {
        const float4* s0 = (const float4*)(xf + nd2[0] * HID + (c0 & 15) * 8);
        const float4* s1 = (const float4*)(xf + nd2[1] * HID + (c1 & 15) * 8);
        pa[0] = s0[0]; pb[0] = s0[1];
        pa[1] = s1[0]; pb[1] = s1[1];
      }
#pragma unroll
      for (int r = 0; r < 4; ++r) attrn[r] = attr[t1 * 16 + quad * 4 + r];
      const int t2 = t1 + NBLK;
      if (t2 < NTILES) {
        nd2[0] = ei[(c0 >> 4) * E_EDGES + t2 * 16 + l15];
        nd2[1] = ei[(c1 >> 4) * E_EDGES + t2 * 16 + l15];
      }
    }

    // 3) layer 1: [16 x 257] @ [257 x 128], K=256 via MFMA + attr column in VALU
    s16x8 A[8];
#pragma unroll
    for (int s = 0; s < 8; ++s)
      A[s] = *(const s16x8*)&ef[((s * 4 + quad) * 16 + l15) * 8];
#pragma unroll
    for (int t = 0; t < 2; ++t) {
      f32x4 acc = {0.f, 0.f, 0.f, 0.f};
#pragma unroll
      for (int s = 0; s < 8; ++s)
        acc = __builtin_amdgcn_mfma_f32_16x16x32_bf16(A[s], B1[t][s], acc, 0, 0, 0);
      const int kk = (wave * 2 + t) * 16 + l15;   // h1 column = layer-2 k index
#pragma unroll
      for (int r = 0; r < 4; ++r) {
        const int m = quad * 4 + r;               // D layout: row = quad*4+reg, col = lane&15
        float v = acc[r] + b1v[t] + attrv[r] * w1l[t];
        v = fmaxf(v, 0.f);
        h1b[((kk >> 3) * 16 + m) * 8 + (kk & 7)] = f2bf(v);
      }
    }
    __syncthreads();

    // 4) layer 2 (MFMA, waves 0,1) + layer 3 (shuffle reduction)
    if (wave < 2) {
      s16x8 A2[4];
#pragma unroll
      for (int s = 0; s < 4; ++s)
        A2[s] = *(const s16x8*)&h1b[((s * 4 + quad) * 16 + l15) * 8];
      f32x4 acc = {0.f, 0.f, 0.f, 0.f};
#pragma unroll
      for (int s = 0; s < 4; ++s)
        acc = __builtin_amdgcn_mfma_f32_16x16x32_bf16(A2[s], B2[s], acc, 0, 0, 0);
      float p0 = fmaxf(acc[0] + b2v, 0.f) * w3v;
      float p1 = fmaxf(acc[1] + b2v, 0.f) * w3v;
      float p2 = fmaxf(acc[2] + b2v, 0.f) * w3v;
      float p3 = fmaxf(acc[3] + b2v, 0.f) * w3v;
#pragma unroll
      for (int off = 8; off >= 1; off >>= 1) {
        p0 += __shfl_xor(p0, off, 16);
        p1 += __shfl_xor(p1, off, 16);
        p2 += __shfl_xor(p2, off, 16);
        p3 += __shfl_xor(p3, off, 16);
      }
      if (l15 == 0) {
        red[wave][quad * 4 + 0] = p0;
        red[wave][quad * 4 + 1] = p1;
        red[wave][quad * 4 + 2] = p2;
        red[wave][quad * 4 + 3] = p3;
      }
    }
    __syncthreads();

    // 5) sigmoid + store (16 edges)
    if (tid < 16) {
      const float s = red[0][tid] + red[1][tid] + b3v;
      out[tile * 16 + tid] = 1.f / (1.f + __expf(-s));
    }

#pragma unroll
    for (int r = 0; r < 4; ++r) attrv[r] = attrn[r];
  }
}

extern "C" void kernel_launch(void* const* d_in, const int* in_sizes, int n_in,
                              void* d_out, int out_size, void* d_ws, size_t ws_size,
                              hipStream_t stream) {
  const float* x    = (const float*)d_in[0];
  const int*   ei   = (const int*)d_in[1];
  const float* attr = (const float*)d_in[2];
  const float* W1   = (const float*)d_in[3];
  const float* b1   = (const float*)d_in[4];
  const float* W2   = (const float*)d_in[5];
  const float* b2   = (const float*)d_in[6];
  const float* W3   = (const float*)d_in[7];
  const float* b3   = (const float*)d_in[8];
  float* out = (float*)d_out;

  const size_t need = (size_t)NNODES * HID * sizeof(unsigned short);  // 25.6 MB
  if (ws_size >= need) {
    unsigned short* xb = (unsigned short*)d_ws;
    // 100000*128 = 12.8M elems, 8/thread -> 1.6M threads = 6250 blocks exact
    cast_x_kernel<<<6250, 256, 0, stream>>>(x, xb);
    edge_mlp_kernel<true><<<NBLK, 256, 0, stream>>>(xb, x, ei, attr, W1, b1, W2, b2, W3, b3, out);
  } else {
    edge_mlp_kernel<false><<<NBLK, 256, 0, stream>>>(nullptr, x, ei, attr, W1, b1, W2, b2, W3, b3, out);
  }
}

// Round 3
// 248.680 us; speedup vs baseline: 1.1384x; 1.1384x over previous
//
#include <hip/hip_runtime.h>

#define E_EDGES 1000000
#define NNODES  100000
#define HID     128
#define NG      31250     // 32-edge groups, exact
#define NBLK    768       // 3 blocks/CU x 256 CUs

typedef float f32x4 __attribute__((ext_vector_type(4)));
typedef short s16x8 __attribute__((ext_vector_type(8)));

// float -> bf16, round-to-nearest-even (inputs are finite)
__device__ __forceinline__ unsigned short f2bf(float f) {
  unsigned int u = __float_as_uint(f);
  u += 0x7FFFu + ((u >> 16) & 1u);
  return (unsigned short)(u >> 16);
}

__device__ __forceinline__ int4 pack8(float4 a, float4 b) {
  int4 v;
  v.x = (int)((unsigned)f2bf(a.x) | ((unsigned)f2bf(a.y) << 16));
  v.y = (int)((unsigned)f2bf(a.z) | ((unsigned)f2bf(a.w) << 16));
  v.z = (int)((unsigned)f2bf(b.x) | ((unsigned)f2bf(b.y) << 16));
  v.w = (int)((unsigned)f2bf(b.z) | ((unsigned)f2bf(b.w) << 16));
  return v;
}

// x fp32 [NNODES*HID] -> bf16 in ws. 12.8M elems / 8 per thread.
__global__ void cast_x_kernel(const float* __restrict__ x,
                              unsigned short* __restrict__ xb) {
  int i = blockIdx.x * blockDim.x + threadIdx.x;
  const float4* p = (const float4*)x;
  float4 a = p[2 * i];
  float4 b = p[2 * i + 1];
  int4 v = pack8(a, b);
  ((int4*)xb)[i] = v;
}

// XOR-swizzled LDS layouts. Chunk = 16B = 8 bf16 of K.
// ef: 2 tiles x 16 rows x 32 chunks. Swizzle low-3 chunk bits with row so
// both the row-major writes (lanes vary chunk) and the MFMA-A reads (lanes
// vary row) spread across bank groups (2-way max = free).
__device__ __forceinline__ int EF(int t, int m, int c) {
  return t * 8192 + m * 512 + ((((c ^ m) & 7) | (c & 24)) << 4);
}
// h1: 2 tiles x 16 rows x 16 chunks
__device__ __forceinline__ int H1(int t, int m, int c2) {
  return t * 4096 + m * 256 + ((((c2 ^ m) & 7) | (c2 & 8)) << 4);
}

// Block = 256 threads = 4 waves, grid-strides over 32-edge groups (2 tiles).
// Gather: 16 contiguous lanes read 16 contiguous chunks of ONE row (256B
// coalesced, 4 full cache lines); 4 rows per wave-instruction.
template <bool PRE>
__launch_bounds__(256, 3)
__global__ void edge_mlp_kernel(const unsigned short* __restrict__ xb,
                                const float* __restrict__ xf,
                                const int* __restrict__ ei,
                                const float* __restrict__ attr,
                                const float* __restrict__ W1,
                                const float* __restrict__ b1,
                                const float* __restrict__ W2,
                                const float* __restrict__ b2,
                                const float* __restrict__ W3,
                                const float* __restrict__ b3,
                                float* __restrict__ out) {
  __shared__ __align__(16) unsigned char ef[16384];   // 16 KB
  __shared__ __align__(16) unsigned char h1b[8192];   // 8 KB
  __shared__ float red[4][16];

  const int tid  = threadIdx.x;
  const int w    = tid >> 6;
  const int lane = tid & 63;
  const int q    = lane >> 4;
  const int l15  = lane & 15;
  const int jrow = w * 4 + q;     // row 0..15 handled by this lane's quad

  // ---- layer-1 weight fragments: wave w owns output cols 32w..32w+31 ----
  s16x8 B1[2][8];
  float b1v[2], w1l[2];
#pragma unroll
  for (int th = 0; th < 2; ++th) {
    const int nc = (w * 2 + th) * 16 + l15;
#pragma unroll
    for (int s = 0; s < 8; ++s)
#pragma unroll
      for (int j = 0; j < 8; ++j)
        B1[th][s][j] = (short)f2bf(W1[(s * 32 + q * 8 + j) * HID + nc]);
    b1v[th] = b1[nc];
    w1l[th] = W1[256 * HID + nc];   // attr column (k=256)
  }
  // ---- layer-2: wave w -> tile (w>>1), output half (w&1) ----
  const int n2 = (w & 1) * 16 + l15;
  s16x8 B2[4];
#pragma unroll
  for (int s2 = 0; s2 < 4; ++s2)
#pragma unroll
    for (int j = 0; j < 8; ++j)
      B2[s2][j] = (short)f2bf(W2[(s2 * 32 + q * 8 + j) * 32 + n2]);
  const float b2v = b2[n2];
  const float w3v = W3[n2];
  const float b3v = b3[0];

  int g = blockIdx.x;
  int nd2[4];
  int4 pv[4];
  float4 pa[4], pb[4];

  // ---- pipeline prologue ----
  if (g < NG) {
    const int base = g * 32;
#pragma unroll
    for (int gg = 0; gg < 4; ++gg) {
      const int node = ei[(gg >> 1) * E_EDGES + base + (gg & 1) * 16 + jrow];
      if constexpr (PRE) {
        pv[gg] = *(const int4*)(xb + (size_t)node * HID + l15 * 8);
      } else {
        const float4* s = (const float4*)(xf + (size_t)node * HID + l15 * 8);
        pa[gg] = s[0]; pb[gg] = s[1];
      }
    }
    const int g1 = g + NBLK;
    if (g1 < NG) {
      const int base1 = g1 * 32;
#pragma unroll
      for (int gg = 0; gg < 4; ++gg)
        nd2[gg] = ei[(gg >> 1) * E_EDGES + base1 + (gg & 1) * 16 + jrow];
    }
  }

  for (; g < NG; g += NBLK) {
    const int base = g * 32;

    // 1) stage gathered rows into swizzled LDS
#pragma unroll
    for (int gg = 0; gg < 4; ++gg) {
      int4 v;
      if constexpr (PRE) v = pv[gg];
      else               v = pack8(pa[gg], pb[gg]);
      const int c = (gg >> 1) * 16 + l15;     // side*16 + chunk
      *(int4*)(ef + EF(gg & 1, jrow, c)) = v;
    }
    __syncthreads();

    // 2) prefetch next group's gathers; ids two groups ahead
    const int g1 = g + NBLK;
    if (g1 < NG) {
#pragma unroll
      for (int gg = 0; gg < 4; ++gg) {
        const int node = nd2[gg];
        if constexpr (PRE) {
          pv[gg] = *(const int4*)(xb + (size_t)node * HID + l15 * 8);
        } else {
          const float4* s = (const float4*)(xf + (size_t)node * HID + l15 * 8);
          pa[gg] = s[0]; pb[gg] = s[1];
        }
      }
      const int g2 = g1 + NBLK;
      if (g2 < NG) {
        const int base2 = g2 * 32;
#pragma unroll
        for (int gg = 0; gg < 4; ++gg)
          nd2[gg] = ei[(gg >> 1) * E_EDGES + base2 + (gg & 1) * 16 + jrow];
      }
    }

    // 3) layer 1: per tile, [16 x 257] @ [257 x 128]
#pragma unroll
    for (int t = 0; t < 2; ++t) {
      const f32x4 a4 = *(const f32x4*)(attr + base + t * 16 + q * 4);
      f32x4 acc0 = {0.f, 0.f, 0.f, 0.f};
      f32x4 acc1 = {0.f, 0.f, 0.f, 0.f};
#pragma unroll
      for (int s = 0; s < 8; ++s) {
        const s16x8 A = *(const s16x8*)(ef + EF(t, l15, s * 4 + q));
        acc0 = __builtin_amdgcn_mfma_f32_16x16x32_bf16(A, B1[0][s], acc0, 0, 0, 0);
        acc1 = __builtin_amdgcn_mfma_f32_16x16x32_bf16(A, B1[1][s], acc1, 0, 0, 0);
      }
#pragma unroll
      for (int th = 0; th < 2; ++th) {
        const f32x4 acc = th ? acc1 : acc0;
        const int n  = (w * 2 + th) * 16 + l15;
        const int c2 = n >> 3;
#pragma unroll
        for (int r = 0; r < 4; ++r) {
          const int m = q * 4 + r;             // D: row = quad*4+reg, col = lane&15
          float v = acc[r] + b1v[th] + a4[r] * w1l[th];
          v = fmaxf(v, 0.f);
          *(unsigned short*)(h1b + H1(t, m, c2) + (n & 7) * 2) = f2bf(v);
        }
      }
    }
    __syncthreads();

    // 4) layer 2 + 3: all 4 waves active (tile = w>>1, half = w&1)
    {
      const int t = w >> 1;
      f32x4 acc = {0.f, 0.f, 0.f, 0.f};
#pragma unroll
      for (int s2 = 0; s2 < 4; ++s2) {
        const s16x8 A2 = *(const s16x8*)(h1b + H1(t, l15, s2 * 4 + q));
        acc = __builtin_amdgcn_mfma_f32_16x16x32_bf16(A2, B2[s2], acc, 0, 0, 0);
      }
      float p[4];
#pragma unroll
      for (int r = 0; r < 4; ++r)
        p[r] = fmaxf(acc[r] + b2v, 0.f) * w3v;
#pragma unroll
      for (int off = 8; off >= 1; off >>= 1)
#pragma unroll
        for (int r = 0; r < 4; ++r)
          p[r] += __shfl_xor(p[r], off, 16);
      if (l15 == 0) {
#pragma unroll
        for (int r = 0; r < 4; ++r)
          red[w][q * 4 + r] = p[r];
      }
    }
    __syncthreads();

    // 5) sigmoid + store (32 edges)
    if (tid < 32) {
      const int t = tid >> 4, m = tid & 15;
      const float s = red[t * 2][m] + red[t * 2 + 1][m] + b3v;
      out[base + tid] = 1.f / (1.f + __expf(-s));
    }
  }
}

extern "C" void kernel_launch(void* const* d_in, const int* in_sizes, int n_in,
                              void* d_out, int out_size, void* d_ws, size_t ws_size,
                              hipStream_t stream) {
  const float* x    = (const float*)d_in[0];
  const int*   ei   = (const int*)d_in[1];
  const float* attr = (const float*)d_in[2];
  const float* W1   = (const float*)d_in[3];
  const float* b1   = (const float*)d_in[4];
  const float* W2   = (const float*)d_in[5];
  const float* b2   = (const float*)d_in[6];
  const float* W3   = (const float*)d_in[7];
  const float* b3   = (const float*)d_in[8];
  float* out = (float*)d_out;

  const size_t need = (size_t)NNODES * HID * sizeof(unsigned short);  // 25.6 MB
  if (ws_size >= need) {
    unsigned short* xb = (unsigned short*)d_ws;
    cast_x_kernel<<<6250, 256, 0, stream>>>(x, xb);
    edge_mlp_kernel<true><<<NBLK, 256, 0, stream>>>(xb, x, ei, attr, W1, b1, W2, b2, W3, b3, out);
  } else {
    edge_mlp_kernel<false><<<NBLK, 256, 0, stream>>>(nullptr, x, ei, attr, W1, b1, W2, b2, W3, b3, out);
  }
}